// Round 3
// baseline (444.808 us; speedup 1.0000x reference)
//
#include <hip/hip_runtime.h>
#include <hip/hip_bf16.h>

// MHGAT: B=8, J=2048, C=256, K=32, H=8, D=32; M = B*J = 16384
// Round 3: runtime dtype detection (bf16 vs fp32) — removes the assumption
// that burned rounds 1-2. Internal q/k/v staging is always fp32.

__device__ __forceinline__ float bf2f(unsigned short u) {
    union { unsigned int i; float f; } c; c.i = ((unsigned int)u) << 16; return c.f;
}
__device__ __forceinline__ unsigned short f2bf(float f) {
    union { float f; unsigned int i; } c; c.f = f;
    unsigned int r = c.i + 0x7FFFu + ((c.i >> 16) & 1u);  // RNE
    return (unsigned short)(r >> 16);
}

template<bool BF16>
__device__ __forceinline__ float ld1(const void* p, size_t i) {
    if (BF16) return bf2f(((const unsigned short*)p)[i]);
    return ((const float*)p)[i];
}
template<bool BF16>
__device__ __forceinline__ void ld4v(const void* p, size_t i, float o[4]) {
    if (BF16) {
        ushort4 u = *(const ushort4*)((const unsigned short*)p + i);
        o[0] = bf2f(u.x); o[1] = bf2f(u.y); o[2] = bf2f(u.z); o[3] = bf2f(u.w);
    } else {
        float4 f = *(const float4*)((const float*)p + i);
        o[0] = f.x; o[1] = f.y; o[2] = f.z; o[3] = f.w;
    }
}

// Block-uniform dtype probe. w points at a weight matrix whose true values are
// uniform(-1/16, 1/16). If the buffer is bf16, ALL of the first 128 u16 words
// decode to |v| <= 0.0625. If it's fp32, half those words are raw mantissa
// bits (uniform random u16): P(all <= 0.0625) ~ 0.48^64 ~ 3e-21. NaN decodes
// fail the <= test too. Deterministic -> identical every call (graph-safe).
__device__ __forceinline__ bool detect_bf16(const void* w, int tid, int* flag) {
    if (tid == 0) *flag = 0;
    __syncthreads();
    if (tid < 128) {
        float v = bf2f(((const unsigned short*)w)[tid]);
        if (!(fabsf(v) <= 0.0625f)) atomicOr(flag, 1);
    }
    __syncthreads();
    return *flag == 0;
}

// ---------------------------------------------------------------------------
// QKV projection, one batch: X[2048,256] @ W[256,256] -> fp32 Y[2048,256].
// 64x64 tile / 256 threads, 4x4 register blocking. blockIdx.z picks Wq/Wk/Wv.
// ---------------------------------------------------------------------------
template<bool BF16>
__device__ void qkv_impl(const void* __restrict__ X, size_t xoff,
                         const void* __restrict__ W, float* __restrict__ Y,
                         float (*Xs)[65], float (*Ws)[69])
{
    const int row0 = blockIdx.x * 64;
    const int col0 = blockIdx.y * 64;
    const int tid  = threadIdx.x;
    const int tn = tid & 15, tm = tid >> 4;
    float acc[4][4] = {};

    for (int k0 = 0; k0 < 256; k0 += 64) {
#pragma unroll
        for (int l = 0; l < 4; l++) {
            int o  = tid + l * 256;       // quad index 0..1023
            int r  = o >> 4;              // tile row 0..63
            int c4 = (o & 15) << 2;       // tile col {0,4,...,60}
            float t4[4];
            ld4v<BF16>(X, xoff + (size_t)(row0 + r) * 256 + k0 + c4, t4);
#pragma unroll
            for (int t = 0; t < 4; t++) Xs[c4 + t][r] = t4[t];
            ld4v<BF16>(W, (size_t)(k0 + r) * 256 + col0 + c4, t4);
#pragma unroll
            for (int t = 0; t < 4; t++) Ws[r][c4 + t] = t4[t];
        }
        __syncthreads();

#pragma unroll
        for (int kk = 0; kk < 64; kk++) {
            float a[4], b[4];
#pragma unroll
            for (int i = 0; i < 4; i++) a[i] = Xs[kk][tm * 4 + i];
#pragma unroll
            for (int j = 0; j < 4; j++) b[j] = Ws[kk][tn * 4 + j];
#pragma unroll
            for (int i = 0; i < 4; i++)
#pragma unroll
                for (int j = 0; j < 4; j++)
                    acc[i][j] += a[i] * b[j];
        }
        __syncthreads();
    }

#pragma unroll
    for (int i = 0; i < 4; i++) {
        float4 o4 = make_float4(acc[i][0], acc[i][1], acc[i][2], acc[i][3]);
        *(float4*)(Y + (size_t)(row0 + tm * 4 + i) * 256 + col0 + tn * 4) = o4;
    }
}

__global__ __launch_bounds__(256) void qkv_gemm(
    const void* __restrict__ X, size_t xoff,
    const void* __restrict__ Wq, const void* __restrict__ Wk,
    const void* __restrict__ Wv,
    float* __restrict__ Q, float* __restrict__ Kp, float* __restrict__ Vp)
{
    __shared__ float Xs[64][65];
    __shared__ float Ws[64][69];
    __shared__ int flag;
    bool isbf = detect_bf16(Wq, threadIdx.x, &flag);

    const void* W = (blockIdx.z == 0) ? Wq : (blockIdx.z == 1) ? Wk : Wv;
    float*      Y = (blockIdx.z == 0) ? Q  : (blockIdx.z == 1) ? Kp : Vp;

    if (isbf) qkv_impl<true >(X, xoff, W, Y, Xs, Ws);
    else      qkv_impl<false>(X, xoff, W, Y, Xs, Ws);
}

// ---------------------------------------------------------------------------
// Per-batch attention + projection. One block per j. q/k/v fp32 (workspace),
// Wp/out in detected dtype. nbr pointer pre-offset (int32, dtype known).
// ---------------------------------------------------------------------------
__global__ __launch_bounds__(256) void attn_batch(
    const float* __restrict__ q, const float* __restrict__ k,
    const float* __restrict__ v,
    const int* __restrict__ nbr,
    const void* __restrict__ Wp,
    void* __restrict__ out, size_t ooff)
{
    __shared__ int   flag;
    __shared__ float qs[256];
    __shared__ int   nb[32];
    __shared__ float sc[32][8];
    __shared__ float pw[32][8];
    __shared__ float hd[256];
    __shared__ float red[8][32];

    const int j = blockIdx.x, tid = threadIdx.x;
    bool isbf = detect_bf16(Wp, tid, &flag);

    qs[tid] = q[(size_t)j * 256 + tid];
    if (tid < 32) nb[tid] = nbr[(size_t)j * 32 + tid];
    __syncthreads();

    const int h = tid & 7, kk = tid >> 3;

    // scores
    float s;
    {
        const float* kr = k + (size_t)nb[kk] * 256 + h * 32;
        float acc = 0.f;
#pragma unroll
        for (int d = 0; d < 32; d++) acc += qs[h * 32 + d] * kr[d];
        s = acc * 0.17677669529663687f;   // 1/sqrt(32)
        s = (s > 0.f) ? s : 0.2f * s;     // leaky_relu 0.2
        sc[kk][h] = s;
    }
    __syncthreads();

    // softmax over K per head
    float mx = -1e30f;
#pragma unroll
    for (int i = 0; i < 32; i++) mx = fmaxf(mx, sc[i][h]);
    float ssum = 0.f;
#pragma unroll
    for (int i = 0; i < 32; i++) ssum += __expf(sc[i][h] - mx);
    pw[kk][h] = __expf(s - mx) / ssum;
    __syncthreads();

    // PV
    {
        const int h2 = tid >> 5;
        float acc = 0.f;
#pragma unroll 8
        for (int i = 0; i < 32; i++)
            acc += pw[i][h2] * v[(size_t)nb[i] * 256 + tid];
        hd[tid] = acc;
    }
    __syncthreads();

    // projection hd[256] @ Wp[256,32], 8-way split-K
    {
        const int c = tid & 31, ch = tid >> 5;
        float p = 0.f;
        if (isbf) {
            const unsigned short* wp = (const unsigned short*)Wp;
#pragma unroll
            for (int i = 0; i < 32; i++) { int r = ch * 32 + i; p += hd[r] * bf2f(wp[r * 32 + c]); }
        } else {
            const float* wp = (const float*)Wp;
#pragma unroll
            for (int i = 0; i < 32; i++) { int r = ch * 32 + i; p += hd[r] * wp[r * 32 + c]; }
        }
        red[ch][c] = p;
    }
    __syncthreads();

    if (tid < 32) {
        float o = 0.f;
#pragma unroll
        for (int i = 0; i < 8; i++) o += red[i][tid];
        size_t oi = ooff + (size_t)j * 32 + tid;
        if (isbf) ((unsigned short*)out)[oi] = f2bf(o);
        else      ((float*)out)[oi] = o;
    }
}

// ---------------------------------------------------------------------------
// Tier 0: fully fused zero-workspace fallback (slow, correct for any ws_size).
// ---------------------------------------------------------------------------
struct FSm {
    float xr[256], qrow[256], xn[256];
    float vn[32][256];
    int   nb[32];
    float sc[32][8], pw[32][8];
    float sp[256], hd[256];
    float red[8][32];
};

template<bool BF16>
__device__ void fused_impl(const void* __restrict__ X, const int* __restrict__ nbr,
                           const void* __restrict__ Wq, const void* __restrict__ Wk,
                           const void* __restrict__ Wv, const void* __restrict__ Wp,
                           void* __restrict__ out, FSm* sm)
{
    const int bj = blockIdx.x, b = bj >> 11, tid = threadIdx.x;

    sm->xr[tid] = ld1<BF16>(X, (size_t)bj * 256 + tid);
    if (tid < 32) sm->nb[tid] = nbr[(size_t)bj * 32 + tid];
    __syncthreads();

    {
        float acc = 0.f;
#pragma unroll 8
        for (int c = 0; c < 256; c++) acc += sm->xr[c] * ld1<BF16>(Wq, (size_t)c * 256 + tid);
        sm->qrow[tid] = acc;
    }
    __syncthreads();

    for (int i = 0; i < 32; i++) {
        size_t r = (size_t)(b * 2048 + sm->nb[i]);
        sm->xn[tid] = ld1<BF16>(X, r * 256 + tid);
        __syncthreads();

        float ka = 0.f, va = 0.f;
#pragma unroll 8
        for (int c = 0; c < 256; c++) {
            float xc = sm->xn[c];
            ka += xc * ld1<BF16>(Wk, (size_t)c * 256 + tid);
            va += xc * ld1<BF16>(Wv, (size_t)c * 256 + tid);
        }
        sm->vn[i][tid] = va;
        sm->sp[tid] = sm->qrow[tid] * ka;
        __syncthreads();

        if (tid < 8) {
            float s = 0.f;
#pragma unroll
            for (int d = 0; d < 32; d++) s += sm->sp[tid * 32 + d];
            s *= 0.17677669529663687f;
            s = (s > 0.f) ? s : 0.2f * s;
            sm->sc[i][tid] = s;
        }
        __syncthreads();
    }

    {
        const int h = tid & 7, kk = tid >> 3;
        float mx = -1e30f;
#pragma unroll
        for (int i = 0; i < 32; i++) mx = fmaxf(mx, sm->sc[i][h]);
        float ssum = 0.f;
#pragma unroll
        for (int i = 0; i < 32; i++) ssum += __expf(sm->sc[i][h] - mx);
        sm->pw[kk][h] = __expf(sm->sc[kk][h] - mx) / ssum;
    }
    __syncthreads();

    {
        const int h2 = tid >> 5;
        float acc = 0.f;
#pragma unroll 8
        for (int i = 0; i < 32; i++) acc += sm->pw[i][h2] * sm->vn[i][tid];
        sm->hd[tid] = acc;
    }
    __syncthreads();

    {
        const int c = tid & 31, ch = tid >> 5;
        float p = 0.f;
#pragma unroll
        for (int i = 0; i < 32; i++) { int r = ch * 32 + i; p += sm->hd[r] * ld1<BF16>(Wp, (size_t)r * 32 + c); }
        sm->red[ch][c] = p;
    }
    __syncthreads();

    if (tid < 32) {
        float o = 0.f;
#pragma unroll
        for (int i = 0; i < 8; i++) o += sm->red[i][tid];
        size_t oi = (size_t)bj * 32 + tid;
        if (BF16) ((unsigned short*)out)[oi] = f2bf(o);
        else      ((float*)out)[oi] = o;
    }
}

__global__ __launch_bounds__(256) void fused_all(
    const void* __restrict__ X, const int* __restrict__ nbr,
    const void* __restrict__ Wq, const void* __restrict__ Wk,
    const void* __restrict__ Wv, const void* __restrict__ Wp,
    void* __restrict__ out)
{
    __shared__ FSm sm;
    __shared__ int flag;
    bool isbf = detect_bf16(Wq, threadIdx.x, &flag);
    if (isbf) fused_impl<true >(X, nbr, Wq, Wk, Wv, Wp, out, &sm);
    else      fused_impl<false>(X, nbr, Wq, Wk, Wv, Wp, out, &sm);
}

extern "C" void kernel_launch(void* const* d_in, const int* in_sizes, int n_in,
                              void* d_out, int out_size, void* d_ws, size_t ws_size,
                              hipStream_t stream) {
    const void* x   = d_in[0];               // [8,2048,256] fp32 or bf16
    const int*  nbr = (const int*)d_in[1];   // [8,2048,32] int32
    const void* Wq  = d_in[2];               // [256,256]
    const void* Wk  = d_in[3];
    const void* Wv  = d_in[4];
    const void* Wp  = d_in[5];               // [256,32]
    void*       out = d_out;                 // [8,2048,32]

    const size_t perb = (size_t)2048 * 256;                 // elements per batch
    const size_t need = 3 * perb * sizeof(float);           // 6 MB fp32 q/k/v

    if (ws_size >= need) {
        float* q = (float*)d_ws;
        float* k = q + perb;
        float* v = k + perb;
        for (int b = 0; b < 8; b++) {
            qkv_gemm<<<dim3(32, 4, 3), 256, 0, stream>>>(
                x, (size_t)b * perb, Wq, Wk, Wv, q, k, v);
            attn_batch<<<2048, 256, 0, stream>>>(
                q, k, v, nbr + (size_t)b * 2048 * 32, Wp,
                out, (size_t)b * 2048 * 32);
        }
    } else {
        fused_all<<<16384, 256, 0, stream>>>(x, nbr, Wq, Wk, Wv, Wp, out);
    }
}

// Round 4
// 189.639 us; speedup vs baseline: 2.3456x; 2.3456x over previous
//
#include <hip/hip_runtime.h>
#include <hip/hip_bf16.h>

// MHGAT: B=8, J=2048, C=256, K=32, H=8, D=32; M = B*J = 16384
// World (confirmed round 3): all float tensors fp32; nbr int32; out fp32.
// Round 4: QKV projection via bf16 MFMA (m97-style: 128x128 tile,
// global_load_lds width-16, 16x16x32 MFMA, fp32 accum); single full-batch
// attention launch with XCD-aware swizzle. q/k/v staged fp32 in d_ws.

typedef short bf16x8 __attribute__((ext_vector_type(8)));
typedef float f32x4  __attribute__((ext_vector_type(4)));

__device__ __forceinline__ unsigned short f2bf(float f) {
    union { float f; unsigned int i; } c; c.f = f;
    unsigned int r = c.i + 0x7FFFu + ((c.i >> 16) & 1u);  // RNE
    return (unsigned short)(r >> 16);
}

// async 16B global->LDS (DMA, no VGPR round-trip). LDS dest must be linear in
// lane order (wave-uniform base + lane*16) — our slot layout satisfies this.
__device__ __forceinline__ void gld_lds16(void* lds, const void* g) {
    __builtin_amdgcn_global_load_lds(
        (const __attribute__((address_space(1))) unsigned int*)g,
        (__attribute__((address_space(3))) unsigned int*)lds,
        16, 0, 0);
}

// ---------------------------------------------------------------------------
// Convert x fp32 -> bf16, 4 elems/thread.
// ---------------------------------------------------------------------------
__global__ __launch_bounds__(256) void cvt_x(
    const float* __restrict__ x, unsigned short* __restrict__ xb, int n4)
{
    int t = blockIdx.x * 256 + threadIdx.x;
    if (t >= n4) return;
    float4 f = ((const float4*)x)[t];
    ushort4 u;
    u.x = f2bf(f.x); u.y = f2bf(f.y); u.z = f2bf(f.z); u.w = f2bf(f.w);
    ((ushort4*)xb)[t] = u;
}

// ---------------------------------------------------------------------------
// Convert Wq/Wk/Wv fp32 [256,256] -> bf16 TRANSPOSED Wt[w][n][k] (so MFMA's
// B operand reads 8 contiguous k at fixed n). One block per (w, n).
// ---------------------------------------------------------------------------
__global__ __launch_bounds__(256) void cvt_w(
    const float* __restrict__ Wq, const float* __restrict__ Wk,
    const float* __restrict__ Wv, unsigned short* __restrict__ Wt)
{
    int w = blockIdx.x >> 8;
    int n = blockIdx.x & 255;
    int t = threadIdx.x;                       // k index
    const float* W = (w == 0) ? Wq : (w == 1) ? Wk : Wv;
    Wt[((size_t)w * 256 + n) * 256 + t] = f2bf(W[(size_t)t * 256 + n]);
}

// ---------------------------------------------------------------------------
// QKV GEMM: xb[16384,256]bf16 @ W[256,256] -> Y fp32 [16384,256].
// BM=128, BN=128, BK=64, 256 threads = 4 waves (2x2), wave tile 64x64 =
// 4x4 frags of 16x16x32 MFMA. Wt is [n][k] so both operands read 8
// contiguous k. blockIdx.z selects weight / output.
// ---------------------------------------------------------------------------
__global__ __launch_bounds__(256) void qkv_mfma(
    const unsigned short* __restrict__ xb,    // [16384,256] bf16
    const unsigned short* __restrict__ Wt,    // [3,256(n),256(k)] bf16
    float* __restrict__ Q, float* __restrict__ Kp, float* __restrict__ Vp)
{
    __shared__ unsigned short Als[128][64];   // 16 KB, [m][k], no pad (DMA-linear)
    __shared__ unsigned short Bls[128][64];   // 16 KB, [n][k]

    const unsigned short* Wb = Wt + (size_t)blockIdx.z * 65536;
    float* Y = (blockIdx.z == 0) ? Q : (blockIdx.z == 1) ? Kp : Vp;

    const int row0 = blockIdx.x * 128;
    const int col0 = blockIdx.y * 128;
    const int tid  = threadIdx.x;
    const int w    = tid >> 6, l = tid & 63;
    const int wm   = (w >> 1) * 64, wn = (w & 1) * 64;
    const int lm   = l & 15, quad = l >> 4;

    f32x4 acc[4][4];
#pragma unroll
    for (int i = 0; i < 4; i++)
#pragma unroll
        for (int j = 0; j < 4; j++) acc[i][j] = (f32x4){0.f, 0.f, 0.f, 0.f};

    const char* Ab = (const char*)(xb + (size_t)row0 * 256);
    const char* Bb = (const char*)(Wb + (size_t)col0 * 256);

    for (int k0 = 0; k0 < 256; k0 += 64) {
        // Stage 128x64 bf16 tiles: 1024 16B-slots each, 4 per thread.
#pragma unroll
        for (int i = 0; i < 4; i++) {
            int s = i * 256 + tid;
            int r = s >> 3, c = s & 7;          // r: tile row, c: 16B chunk
            size_t go = (size_t)r * 512 + (size_t)k0 * 2 + c * 16;
            gld_lds16((char*)Als + s * 16, Ab + go);
            gld_lds16((char*)Bls + s * 16, Bb + go);
        }
        __syncthreads();

#pragma unroll
        for (int kk = 0; kk < 64; kk += 32) {
            bf16x8 a[4], b[4];
#pragma unroll
            for (int tm = 0; tm < 4; tm++)
                a[tm] = *(const bf16x8*)&Als[wm + tm * 16 + lm][kk + quad * 8];
#pragma unroll
            for (int tn = 0; tn < 4; tn++)
                b[tn] = *(const bf16x8*)&Bls[wn + tn * 16 + lm][kk + quad * 8];
#pragma unroll
            for (int tm = 0; tm < 4; tm++)
#pragma unroll
                for (int tn = 0; tn < 4; tn++)
                    acc[tm][tn] = __builtin_amdgcn_mfma_f32_16x16x32_bf16(
                        a[tm], b[tn], acc[tm][tn], 0, 0, 0);
        }
        __syncthreads();
    }

    // Epilogue: C/D layout col=lane&15, row=quad*4+reg (m89-verified).
#pragma unroll
    for (int tm = 0; tm < 4; tm++) {
        int rbase = row0 + wm + tm * 16 + quad * 4;
#pragma unroll
        for (int tn = 0; tn < 4; tn++) {
            int col = col0 + wn + tn * 16 + lm;
#pragma unroll
            for (int r = 0; r < 4; r++)
                Y[(size_t)(rbase + r) * 256 + col] = acc[tm][tn][r];
        }
    }
}

// ---------------------------------------------------------------------------
// Full-batch attention + projection. One block per (b,j).
// XCD swizzle: b = blk&7 so each XCD's L2 caches one batch's k+v (4 MB).
// ---------------------------------------------------------------------------
__global__ __launch_bounds__(256) void attn_all(
    const float* __restrict__ q, const float* __restrict__ k,
    const float* __restrict__ v,
    const int* __restrict__ nbr,
    const float* __restrict__ Wp,             // [256,32] fp32
    float* __restrict__ out)                  // [16384,32] fp32
{
    __shared__ float qs[256];
    __shared__ int   nb[32];
    __shared__ float sc[32][8];
    __shared__ float pw[32][8];
    __shared__ float hd[256];
    __shared__ float red[8][32];

    const int b   = blockIdx.x & 7;
    const int j   = blockIdx.x >> 3;
    const int bj  = (b << 11) + j;
    const int tid = threadIdx.x;

    qs[tid] = q[(size_t)bj * 256 + tid];
    if (tid < 32) nb[tid] = nbr[(size_t)bj * 32 + tid];
    __syncthreads();

    const int h = tid & 7, kk = tid >> 3;

    // scores: leaky_relu((q_h . k_nbr_h)/sqrt(32))
    float s;
    {
        const float4* kr = (const float4*)(k + ((size_t)(b * 2048 + nb[kk])) * 256 + h * 32);
        float acc = 0.f;
#pragma unroll
        for (int d4 = 0; d4 < 8; d4++) {
            float4 kv = kr[d4];
            const float* qp = qs + h * 32 + d4 * 4;
            acc += qp[0] * kv.x + qp[1] * kv.y + qp[2] * kv.z + qp[3] * kv.w;
        }
        s = acc * 0.17677669529663687f;
        s = (s > 0.f) ? s : 0.2f * s;
        sc[kk][h] = s;
    }
    __syncthreads();

    // softmax over K per head
    float mx = -1e30f;
#pragma unroll
    for (int i = 0; i < 32; i++) mx = fmaxf(mx, sc[i][h]);
    float ssum = 0.f;
#pragma unroll
    for (int i = 0; i < 32; i++) ssum += __expf(sc[i][h] - mx);
    pw[kk][h] = __expf(s - mx) / ssum;
    __syncthreads();

    // PV: hd[e] = sum_i pw[i][h(e)] * v[nb_i][e]
    {
        const int h2 = tid >> 5;
        float acc = 0.f;
#pragma unroll 8
        for (int i = 0; i < 32; i++)
            acc += pw[i][h2] * v[((size_t)(b * 2048 + nb[i])) * 256 + tid];
        hd[tid] = acc;
    }
    __syncthreads();

    // projection: hd[256] @ Wp[256,32], 8-way split-K + reduce
    {
        const int c = tid & 31, ch = tid >> 5;
        float p = 0.f;
#pragma unroll
        for (int i = 0; i < 32; i++) {
            int r = ch * 32 + i;
            p += hd[r] * Wp[r * 32 + c];
        }
        red[ch][c] = p;
    }
    __syncthreads();

    if (tid < 32) {
        float o = 0.f;
#pragma unroll
        for (int i = 0; i < 8; i++) o += red[i][tid];
        out[(size_t)bj * 32 + tid] = o;
    }
}

// ---------------------------------------------------------------------------
// Tier 0 fallback (tiny ws): fully fused, zero workspace, fp32. Slow, correct.
// ---------------------------------------------------------------------------
__global__ __launch_bounds__(256) void fused_all(
    const float* __restrict__ X, const int* __restrict__ nbr,
    const float* __restrict__ Wq, const float* __restrict__ Wk,
    const float* __restrict__ Wv, const float* __restrict__ Wp,
    float* __restrict__ out)
{
    __shared__ float xr[256], qrow[256], xn[256];
    __shared__ float vn[32][256];
    __shared__ int   nb[32];
    __shared__ float sc[32][8], pw[32][8];
    __shared__ float sp[256], hd[256];
    __shared__ float red[8][32];

    const int bj = blockIdx.x, b = bj >> 11, tid = threadIdx.x;

    xr[tid] = X[(size_t)bj * 256 + tid];
    if (tid < 32) nb[tid] = nbr[(size_t)bj * 32 + tid];
    __syncthreads();

    {
        float acc = 0.f;
#pragma unroll 8
        for (int c = 0; c < 256; c++) acc += xr[c] * Wq[(size_t)c * 256 + tid];
        qrow[tid] = acc;
    }
    __syncthreads();

    for (int i = 0; i < 32; i++) {
        size_t r = (size_t)(b * 2048 + nb[i]);
        xn[tid] = X[r * 256 + tid];
        __syncthreads();
        float ka = 0.f, va = 0.f;
#pragma unroll 8
        for (int c = 0; c < 256; c++) {
            float xc = xn[c];
            ka += xc * Wk[(size_t)c * 256 + tid];
            va += xc * Wv[(size_t)c * 256 + tid];
        }
        vn[i][tid] = va;
        sp[tid] = qrow[tid] * ka;
        __syncthreads();
        if (tid < 8) {
            float s = 0.f;
#pragma unroll
            for (int d = 0; d < 32; d++) s += sp[tid * 32 + d];
            s *= 0.17677669529663687f;
            s = (s > 0.f) ? s : 0.2f * s;
            sc[i][tid] = s;
        }
        __syncthreads();
    }

    {
        const int h = tid & 7, kk = tid >> 3;
        float mx = -1e30f;
#pragma unroll
        for (int i = 0; i < 32; i++) mx = fmaxf(mx, sc[i][h]);
        float ssum = 0.f;
#pragma unroll
        for (int i = 0; i < 32; i++) ssum += __expf(sc[i][h] - mx);
        pw[kk][h] = __expf(sc[kk][h] - mx) / ssum;
    }
    __syncthreads();

    {
        const int h2 = tid >> 5;
        float acc = 0.f;
#pragma unroll 8
        for (int i = 0; i < 32; i++) acc += pw[i][h2] * vn[i][tid];
        hd[tid] = acc;
    }
    __syncthreads();

    {
        const int c = tid & 31, ch = tid >> 5;
        float p = 0.f;
#pragma unroll
        for (int i = 0; i < 32; i++) { int r = ch * 32 + i; p += hd[r] * Wp[r * 32 + c]; }
        red[ch][c] = p;
    }
    __syncthreads();

    if (tid < 32) {
        float o = 0.f;
#pragma unroll
        for (int i = 0; i < 8; i++) o += red[i][tid];
        out[(size_t)bj * 32 + tid] = o;
    }
}

extern "C" void kernel_launch(void* const* d_in, const int* in_sizes, int n_in,
                              void* d_out, int out_size, void* d_ws, size_t ws_size,
                              hipStream_t stream) {
    const float* x   = (const float*)d_in[0];   // [8,2048,256]
    const int*   nbr = (const int*)d_in[1];     // [8,2048,32]
    const float* Wq  = (const float*)d_in[2];   // [256,256]
    const float* Wk  = (const float*)d_in[3];
    const float* Wv  = (const float*)d_in[4];
    const float* Wp  = (const float*)d_in[5];   // [256,32]
    float*       out = (float*)d_out;           // [8,2048,32]

    const size_t ME   = (size_t)16384 * 256;    // 4,194,304 elems
    // ws layout: xb bf16[ME] | Wt bf16[3*65536] | q,k,v fp32[ME] each
    const size_t need = ME * 2 + 3 * 65536 * 2 + 3 * ME * 4;   // ~59.1 MB

    if (ws_size >= need) {
        unsigned short* xb = (unsigned short*)d_ws;
        unsigned short* Wt = xb + ME;
        float* q = (float*)(Wt + 3 * 65536);
        float* k = q + ME;
        float* v = k + ME;

        cvt_x<<<(int)(ME / 4 / 256), 256, 0, stream>>>(x, xb, (int)(ME / 4));
        cvt_w<<<3 * 256, 256, 0, stream>>>(Wq, Wk, Wv, Wt);
        qkv_mfma<<<dim3(128, 2, 3), 256, 0, stream>>>(xb, Wt, q, k, v);
        attn_all<<<16384, 256, 0, stream>>>(q, k, v, nbr, Wp, out);
    } else {
        fused_all<<<16384, 256, 0, stream>>>(x, nbr, Wq, Wk, Wv, Wp, out);
    }
}

// Round 5
// 161.125 us; speedup vs baseline: 2.7606x; 1.1770x over previous
//
#include <hip/hip_runtime.h>
#include <hip/hip_bf16.h>

// MHGAT: B=8, J=2048, C=256, K=32, H=8, D=32; M = B*J = 16384
// World: all float tensors fp32; nbr int32; out fp32.
// Round 5: (1) Wp folded into Wv (GEMM z=2 emits VP = x @ Weff directly,
// attention loses PV+projection); (2) register softmax via half-wave
// shuffles (lane=(kk,h)); (3) q/k/VP stored bf16.

typedef short bf16x8 __attribute__((ext_vector_type(8)));
typedef float f32x4  __attribute__((ext_vector_type(4)));

__device__ __forceinline__ float bf2f(unsigned short u) {
    union { unsigned int i; float f; } c; c.i = ((unsigned int)u) << 16; return c.f;
}
__device__ __forceinline__ unsigned short f2bf(float f) {
    union { float f; unsigned int i; } c; c.f = f;
    unsigned int r = c.i + 0x7FFFu + ((c.i >> 16) & 1u);  // RNE
    return (unsigned short)(r >> 16);
}

__device__ __forceinline__ void gld_lds16(void* lds, const void* g) {
    __builtin_amdgcn_global_load_lds(
        (const __attribute__((address_space(1))) unsigned int*)g,
        (__attribute__((address_space(3))) unsigned int*)lds,
        16, 0, 0);
}

// ---------------------------------------------------------------------------
// Fused prep: blocks [0,4096): x fp32 -> xb bf16 (4 elems/thread).
// blocks [4096, 4864): weight prep ->
//   Wt[0][n][k] = Wq[k][n],  Wt[1][n][k] = Wk[k][n]  (bf16, transposed)
//   Wt[2][n][k] = Weff[k][n] = sum_d Wv[k][h*32+d] * Wp[h*32+d][c], n=h*32+c
// ---------------------------------------------------------------------------
__global__ __launch_bounds__(256) void prep(
    const float* __restrict__ x,
    const float* __restrict__ Wq, const float* __restrict__ Wk,
    const float* __restrict__ Wv, const float* __restrict__ Wp,
    unsigned short* __restrict__ xb, unsigned short* __restrict__ Wt)
{
    const int blk = blockIdx.x, tid = threadIdx.x;
    if (blk < 4096) {
        int t = blk * 256 + tid;                  // [0, 1048576) = ME/4
        float4 f = ((const float4*)x)[t];
        ushort4 u;
        u.x = f2bf(f.x); u.y = f2bf(f.y); u.z = f2bf(f.z); u.w = f2bf(f.w);
        ((ushort4*)xb)[t] = u;
        return;
    }
    int wi = blk - 4096;                          // [0, 768)
    int w = wi >> 8, n = wi & 255, t = tid;       // t = k index
    if (w == 0) {
        Wt[(size_t)n * 256 + t] = f2bf(Wq[(size_t)t * 256 + n]);
    } else if (w == 1) {
        Wt[(size_t)(256 + n) * 256 + t] = f2bf(Wk[(size_t)t * 256 + n]);
    } else {
        int h = n >> 5, c = n & 31;
        float acc = 0.f;
#pragma unroll
        for (int d = 0; d < 32; d++)
            acc += Wv[(size_t)t * 256 + h * 32 + d] * Wp[(size_t)(h * 32 + d) * 32 + c];
        Wt[(size_t)(512 + n) * 256 + t] = f2bf(acc);
    }
}

// ---------------------------------------------------------------------------
// QKV GEMM: xb[16384,256]bf16 @ Wt[z] -> bf16 [16384,256].
// BM=BN=128, BK=64, 4 waves (2x2), 4x4 frags of 16x16x32 MFMA, fp32 accum.
// z: 0->q, 1->k, 2->VP.
// ---------------------------------------------------------------------------
__global__ __launch_bounds__(256) void qkv_mfma(
    const unsigned short* __restrict__ xb,
    const unsigned short* __restrict__ Wt,
    unsigned short* __restrict__ Q, unsigned short* __restrict__ Kp,
    unsigned short* __restrict__ VP)
{
    __shared__ unsigned short Als[128][64];
    __shared__ unsigned short Bls[128][64];

    const unsigned short* Wb = Wt + (size_t)blockIdx.z * 65536;
    unsigned short* Y = (blockIdx.z == 0) ? Q : (blockIdx.z == 1) ? Kp : VP;

    const int row0 = blockIdx.x * 128;
    const int col0 = blockIdx.y * 128;
    const int tid  = threadIdx.x;
    const int w    = tid >> 6, l = tid & 63;
    const int wm   = (w >> 1) * 64, wn = (w & 1) * 64;
    const int lm   = l & 15, quad = l >> 4;

    f32x4 acc[4][4];
#pragma unroll
    for (int i = 0; i < 4; i++)
#pragma unroll
        for (int j = 0; j < 4; j++) acc[i][j] = (f32x4){0.f, 0.f, 0.f, 0.f};

    const char* Ab = (const char*)(xb + (size_t)row0 * 256);
    const char* Bb = (const char*)(Wb + (size_t)col0 * 256);

    for (int k0 = 0; k0 < 256; k0 += 64) {
#pragma unroll
        for (int i = 0; i < 4; i++) {
            int s = i * 256 + tid;
            int r = s >> 3, c = s & 7;
            size_t go = (size_t)r * 512 + (size_t)k0 * 2 + c * 16;
            gld_lds16((char*)Als + s * 16, Ab + go);
            gld_lds16((char*)Bls + s * 16, Bb + go);
        }
        __syncthreads();

#pragma unroll
        for (int kk = 0; kk < 64; kk += 32) {
            bf16x8 a[4], b[4];
#pragma unroll
            for (int tm = 0; tm < 4; tm++)
                a[tm] = *(const bf16x8*)&Als[wm + tm * 16 + lm][kk + quad * 8];
#pragma unroll
            for (int tn = 0; tn < 4; tn++)
                b[tn] = *(const bf16x8*)&Bls[wn + tn * 16 + lm][kk + quad * 8];
#pragma unroll
            for (int tm = 0; tm < 4; tm++)
#pragma unroll
                for (int tn = 0; tn < 4; tn++)
                    acc[tm][tn] = __builtin_amdgcn_mfma_f32_16x16x32_bf16(
                        a[tm], b[tn], acc[tm][tn], 0, 0, 0);
        }
        __syncthreads();
    }

    // C/D layout: col=lane&15, row=quad*4+reg (m89-verified). bf16 stores.
#pragma unroll
    for (int tm = 0; tm < 4; tm++) {
        int rbase = row0 + wm + tm * 16 + quad * 4;
#pragma unroll
        for (int tn = 0; tn < 4; tn++) {
            int col = col0 + wn + tn * 16 + lm;
#pragma unroll
            for (int r = 0; r < 4; r++)
                Y[(size_t)(rbase + r) * 256 + col] = f2bf(acc[tm][tn][r]);
        }
    }
}

// ---------------------------------------------------------------------------
// Attention: one 256-thread block per (b,j). XCD swizzle b = blk&7.
// Phase A (lane=(kk,h)): score = leaky(q_h . k_nb_h / sqrt(32)); softmax over
//   kk via 5 shfl_xor butterflies in each 32-lane half-wave; pw -> LDS.
// Phase B (thread=(c,h)): out partial = sum_k pw[k,h] * VP[nb_k][h*32+c];
//   8-way h-reduce in LDS.
// ---------------------------------------------------------------------------
__global__ __launch_bounds__(256) void attn_all(
    const unsigned short* __restrict__ qb,   // [16384,256] bf16
    const unsigned short* __restrict__ kb,   // [16384,256] bf16
    const unsigned short* __restrict__ vp,   // [16384,256] bf16 (VP)
    const int*            __restrict__ nbr,  // [16384,32]
    float*                __restrict__ out)  // [16384,32] fp32
{
    __shared__ int   koff[32];    // nb * 256 (element offset)
    __shared__ float pw[8 * 33];  // [h][kk], pad 1
    __shared__ float red[8 * 33]; // [h][c],  pad 1

    const int b   = blockIdx.x & 7;
    const int j   = blockIdx.x >> 3;
    const int bj  = (b << 11) + j;
    const int tid = threadIdx.x;

    if (tid < 32) koff[tid] = nbr[(size_t)bj * 32 + tid] << 8;
    __syncthreads();

    const int wv = tid >> 6, l = tid & 63;
    const int h  = 2 * wv + (l >> 5);
    const int kk = l & 31;

    // q fragment (this lane's head) in registers: 32 fp32 from 4x 16B loads.
    float qr[32];
    {
        const uint4* qp = (const uint4*)(qb + (size_t)bj * 256 + h * 32);
#pragma unroll
        for (int c4 = 0; c4 < 4; c4++) {
            uint4 u = qp[c4];
            const unsigned short* u8 = (const unsigned short*)&u;
#pragma unroll
            for (int t = 0; t < 8; t++) qr[c4 * 8 + t] = bf2f(u8[t]);
        }
    }

    // score: dot(q_h, k[nb_kk]_h)
    float s;
    {
        const unsigned short* kr =
            kb + (size_t)(b << 19) + koff[kk] + h * 32;  // b*2048*256
        float acc = 0.f;
#pragma unroll
        for (int c4 = 0; c4 < 4; c4++) {
            uint4 u = ((const uint4*)kr)[c4];
            const unsigned short* u8 = (const unsigned short*)&u;
#pragma unroll
            for (int t = 0; t < 8; t++) acc += qr[c4 * 8 + t] * bf2f(u8[t]);
        }
        s = acc * 0.17677669529663687f;   // 1/sqrt(32)
        s = (s > 0.f) ? s : 0.2f * s;     // leaky_relu 0.2
    }

    // softmax over kk within the 32-lane half-wave
    float mx = s;
#pragma unroll
    for (int m = 16; m >= 1; m >>= 1) mx = fmaxf(mx, __shfl_xor(mx, m));
    float e = __expf(s - mx);
    float sum = e;
#pragma unroll
    for (int m = 16; m >= 1; m >>= 1) sum += __shfl_xor(sum, m);
    pw[h * 33 + kk] = e / sum;
    __syncthreads();

    // out gather: thread=(c,h2): sum_k pw[h2][k] * VP[nb_k][h2*32+c]
    {
        const int c  = tid & 31;
        const int h2 = tid >> 5;
        const unsigned short* vb2 = vp + (size_t)(b << 19) + h2 * 32 + c;
        float acc = 0.f;
#pragma unroll
        for (int i = 0; i < 32; i++)
            acc += pw[h2 * 33 + i] * bf2f(vb2[koff[i]]);
        red[h2 * 33 + c] = acc;
    }
    __syncthreads();

    if (tid < 32) {
        float o = 0.f;
#pragma unroll
        for (int i = 0; i < 8; i++) o += red[i * 33 + tid];
        out[(size_t)bj * 32 + tid] = o;
    }
}

// ---------------------------------------------------------------------------
// Tier 0 fallback (tiny ws): fully fused fp32, zero workspace. Slow, correct.
// ---------------------------------------------------------------------------
__global__ __launch_bounds__(256) void fused_all(
    const float* __restrict__ X, const int* __restrict__ nbr,
    const float* __restrict__ Wq, const float* __restrict__ Wk,
    const float* __restrict__ Wv, const float* __restrict__ Wp,
    float* __restrict__ out)
{
    __shared__ float xr[256], qrow[256], xn[256];
    __shared__ float vn[32][256];
    __shared__ int   nb[32];
    __shared__ float sc[32][8], pwv[32][8];
    __shared__ float sp[256], hd[256];
    __shared__ float red[8][32];

    const int bj = blockIdx.x, b = bj >> 11, tid = threadIdx.x;

    xr[tid] = X[(size_t)bj * 256 + tid];
    if (tid < 32) nb[tid] = nbr[(size_t)bj * 32 + tid];
    __syncthreads();

    {
        float acc = 0.f;
#pragma unroll 8
        for (int c = 0; c < 256; c++) acc += xr[c] * Wq[(size_t)c * 256 + tid];
        qrow[tid] = acc;
    }
    __syncthreads();

    for (int i = 0; i < 32; i++) {
        size_t r = (size_t)(b * 2048 + nb[i]);
        xn[tid] = X[r * 256 + tid];
        __syncthreads();
        float ka = 0.f, va = 0.f;
#pragma unroll 8
        for (int c = 0; c < 256; c++) {
            float xc = xn[c];
            ka += xc * Wk[(size_t)c * 256 + tid];
            va += xc * Wv[(size_t)c * 256 + tid];
        }
        vn[i][tid] = va;
        sp[tid] = qrow[tid] * ka;
        __syncthreads();
        if (tid < 8) {
            float s = 0.f;
#pragma unroll
            for (int d = 0; d < 32; d++) s += sp[tid * 32 + d];
            s *= 0.17677669529663687f;
            s = (s > 0.f) ? s : 0.2f * s;
            sc[i][tid] = s;
        }
        __syncthreads();
    }

    {
        const int h = tid & 7, kk = tid >> 3;
        float mx = -1e30f;
#pragma unroll
        for (int i = 0; i < 32; i++) mx = fmaxf(mx, sc[i][h]);
        float ssum = 0.f;
#pragma unroll
        for (int i = 0; i < 32; i++) ssum += __expf(sc[i][h] - mx);
        pwv[kk][h] = __expf(sc[kk][h] - mx) / ssum;
    }
    __syncthreads();

    {
        const int h2 = tid >> 5;
        float acc = 0.f;
#pragma unroll 8
        for (int i = 0; i < 32; i++) acc += pwv[i][h2] * vn[i][tid];
        hd[tid] = acc;
    }
    __syncthreads();

    {
        const int c = tid & 31, ch = tid >> 5;
        float p = 0.f;
#pragma unroll
        for (int i = 0; i < 32; i++) { int r = ch * 32 + i; p += hd[r] * Wp[r * 32 + c]; }
        red[ch][c] = p;
    }
    __syncthreads();

    if (tid < 32) {
        float o = 0.f;
#pragma unroll
        for (int i = 0; i < 8; i++) o += red[i][tid];
        out[(size_t)bj * 32 + tid] = o;
    }
}

extern "C" void kernel_launch(void* const* d_in, const int* in_sizes, int n_in,
                              void* d_out, int out_size, void* d_ws, size_t ws_size,
                              hipStream_t stream) {
    const float* x   = (const float*)d_in[0];
    const int*   nbr = (const int*)d_in[1];
    const float* Wq  = (const float*)d_in[2];
    const float* Wk  = (const float*)d_in[3];
    const float* Wv  = (const float*)d_in[4];
    const float* Wp  = (const float*)d_in[5];
    float*       out = (float*)d_out;

    const size_t ME   = (size_t)16384 * 256;
    // ws: q,k,vp,xb bf16[ME] each | Wt bf16[3*65536]
    const size_t need = (4 * ME + 3 * 65536) * sizeof(unsigned short);  // ~34 MB

    if (ws_size >= need) {
        unsigned short* q  = (unsigned short*)d_ws;
        unsigned short* k  = q + ME;
        unsigned short* vp = k + ME;
        unsigned short* xb = vp + ME;
        unsigned short* Wt = xb + ME;

        prep<<<4096 + 768, 256, 0, stream>>>(x, Wq, Wk, Wv, Wp, xb, Wt);
        qkv_mfma<<<dim3(128, 2, 3), 256, 0, stream>>>(xb, Wt, q, k, vp);
        attn_all<<<16384, 256, 0, stream>>>(q, k, vp, nbr, out);
    } else {
        fused_all<<<16384, 256, 0, stream>>>(x, nbr, Wq, Wk, Wv, Wp, out);
    }
}